// Round 15
// baseline (1547.703 us; speedup 1.0000x reference)
//
#include <hip/hip_runtime.h>
#include <hip/hip_cooperative_groups.h>
#include <cmath>

namespace cg = cooperative_groups;

#define NB   8
#define NPG  128
#define NN   1024
#define KNB  64
#define HD   600
#define GG   50
#define LL   6
#define EE   (NN*KNB)     // 65536 edges
#define WROW 640          // padded weight rows (n)
#define WCOL 608          // padded weight cols (k)
#define NKNOT 1024        // W(d) table knots over [0,10]
#define GRIDB 256         // cooperative grid blocks (1/CU — co-residency guaranteed)
#define NTILE 320         // 32 x 10 gemm tiles

typedef __attribute__((ext_vector_type(8))) short short8;
typedef __attribute__((ext_vector_type(4))) short short4v;
typedef __attribute__((ext_vector_type(4))) float f32x4;

__device__ __forceinline__ short f2b(float f) {
  union { float f; unsigned u; } v; v.f = f;
  unsigned u = v.u;
  u += 0x7fffu + ((u >> 16) & 1u);
  return (short)(u >> 16);
}

__device__ __forceinline__ float b2f(unsigned us) {
  union { unsigned u; float f; } v; v.u = us << 16; return v.f;
}

// fast shifted softplus: max(x,0)+log(1+e^-|x|)-ln2
__device__ __forceinline__ float ssp_fast(float x) {
  return fmaxf(x, 0.0f) + __logf(1.0f + __expf(-fabsf(x))) - 0.69314718055994531f;
}

// ---------------- graph build: one block per node ----------------
__global__ __launch_bounds__(128) void build_graph_k(const float* __restrict__ pos,
        int* __restrict__ nbr, float* __restrict__ dist, float* __restrict__ cval) {
#pragma clang fp contract(off)
  __shared__ float d2s[128];
  __shared__ int scnt;
  int i = blockIdx.x;
  int li = i & 127;
  int base = i - li;
  int j = threadIdx.x;
  if (j == 0) scnt = 0;
  float px = pos[3*i], py = pos[3*i+1], pz = pos[3*i+2];
  int gj = base + j;
  float dx = px - pos[3*gj], dy = py - pos[3*gj+1], dz = pz - pos[3*gj+2];
  float d2 = dx*dx + dy*dy + dz*dz;
  bool valid = (j != li) && (d2 <= 100.0f);
  d2s[j] = valid ? d2 : 3.0e38f;
  __syncthreads();
  if (valid) {
    atomicAdd(&scnt, 1);
    int rank = 0;
    for (int j2 = 0; j2 < 128; ++j2) {
      float o = d2s[j2];
      rank += (o < d2 || (o == d2 && j2 < j)) ? 1 : 0;
    }
    if (rank < KNB) {
      int e = i*KNB + rank;
      nbr[e] = gj;
      float d = sqrtf(d2);
      dist[e] = d;
      cval[e] = 0.5f * (cosf(d * 0.31415926535897931f) + 1.0f);
    }
  }
  __syncthreads();
  int cnt = scnt; if (cnt > KNB) cnt = KNB;
  if (j < KNB && j >= cnt) {
    int e = i*KNB + j;
    nbr[e] = i; dist[e] = 0.0f; cval[e] = 0.0f;
  }
}

// ---------------- prep: gaussian basis [NKNOT][64] + w1 conv [6][640][64] ----------------
__global__ __launch_bounds__(256) void prep_k(const float* __restrict__ w1,
    short* __restrict__ basis, short* __restrict__ w1b) {
  int idx = blockIdx.x*256 + threadIdx.x;
  if (idx < NKNOT*64) {
    int i = idx >> 6, g = idx & 63;
    float v = 0.0f;
    if (g < GG) {
      const float step = 10.0f/49.0f;
      const float coeff = -0.5f/(step*step);
      float d = (float)i * (10.0f/(float)(NKNOT-1));
      float dd = d - step*(float)g;
      v = __expf(coeff*dd*dd);
    }
    basis[idx] = f2b(v);
  } else {
    int r = idx - NKNOT*64;
    if (r >= LL*WROW*64) return;
    int l = r / (WROW*64); int rem = r - l*WROW*64;
    int n = rem >> 6, k = rem & 63;
    float v = (n < HD && k < GG) ? w1[(size_t)l*GG*HD + (size_t)k*HD + n] : 0.0f;
    w1b[r] = f2b(v);
  }
}

// ---------------- all node/w2 weights: LDS-tiled transpose ----------------
__global__ __launch_bounds__(256) void conv_all_k(const float* __restrict__ l1w,
    const float* __restrict__ l2w, const float* __restrict__ ilw,
    const float* __restrict__ w2, short* __restrict__ dst) {
  __shared__ float T[64][65];
  int w = blockIdx.x;
  int kind = w / 6, l = w - kind*6;
  const float* s = (kind == 0) ? l1w : (kind == 1) ? l2w : (kind == 2) ? ilw : w2;
  s += (size_t)l*360000;
  int n0 = blockIdx.y*64, k0 = blockIdx.z*64;
  int tid = threadIdx.x;
  int ta = tid & 63, tb = tid >> 6;
  #pragma unroll
  for (int p = 0; p < 16; ++p) {
    int k = k0 + p*4 + tb;
    int n = n0 + ta;
    T[p*4 + tb][ta] = (k < HD && n < HD) ? s[(size_t)k*HD + n] : 0.0f;
  }
  __syncthreads();
  #pragma unroll
  for (int p = 0; p < 16; ++p) {
    int n = n0 + p*4 + tb;
    int k = k0 + ta;
    if (k < WCOL)
      dst[(size_t)w*WROW*WCOL + (size_t)n*WCOL + k] = f2b(T[ta][p*4 + tb]);
  }
}

// ---------------- embedding: h fp32 + h_b bf16 ----------------
__global__ __launch_bounds__(256) void embed_k(const int* __restrict__ z,
        const float* __restrict__ emb, float* __restrict__ h, short* __restrict__ hb) {
  int i = blockIdx.x;
  int zi = z[i];
  for (int j = threadIdx.x; j < WCOL; j += 256) {
    float v = (j < HD) ? emb[(size_t)zi*HD + j] : 0.0f;
    if (j < HD) h[(size_t)i*HD + j] = v;
    hb[(size_t)i*WCOL + j] = f2b(v);
  }
}

// ---------------- tabA: ttab_all[l] = bf16(ssp(basis@w1[l]+b1[l])) ----------------
__global__ __launch_bounds__(256) void tabA_k(const short* __restrict__ basis,
    const short* __restrict__ w1b, const float* __restrict__ b1all,
    short* __restrict__ ttab_all) {
  const int MT = NKNOT/128;
  int l = blockIdx.x / MT;
  int mb = blockIdx.x - l*MT;
  const short* Bw = w1b + (size_t)l*WROW*64;
  short* outb = ttab_all + (size_t)l*NKNOT*WCOL;
  __shared__ __align__(16) short As[128*40];
  __shared__ __align__(16) short Bs[128*40];
  int tid = threadIdx.x;
  int lane = tid & 63, wv = tid >> 6;
  int wr = wv >> 1, wc = wv & 1;
  int col = lane & 15, quad = lane >> 4;
  int m0 = mb * 128;
  int n0 = blockIdx.y * 128;
  f32x4 acc[4][4] = {};
  for (int k0 = 0; k0 < 64; k0 += 32) {
    #pragma unroll
    for (int rep = 0; rep < 2; ++rep) {
      int s = tid + rep*256;
      int row = s >> 2, seg = s & 3;
      *(short8*)&As[row*40 + seg*8] =
          *(const short8*)(basis + (size_t)(m0 + row)*64 + k0 + seg*8);
      *(short8*)&Bs[row*40 + seg*8] =
          *(const short8*)(Bw + (size_t)(n0 + row)*64 + k0 + seg*8);
    }
    __syncthreads();
    short8 af[4], bf[4];
    #pragma unroll
    for (int mt = 0; mt < 4; ++mt)
      af[mt] = *(const short8*)&As[(wr*64 + mt*16 + col)*40 + quad*8];
    #pragma unroll
    for (int jt = 0; jt < 4; ++jt)
      bf[jt] = *(const short8*)&Bs[(wc*64 + jt*16 + col)*40 + quad*8];
    #pragma unroll
    for (int mt = 0; mt < 4; ++mt)
      #pragma unroll
      for (int jt = 0; jt < 4; ++jt)
        acc[mt][jt] = __builtin_amdgcn_mfma_f32_16x16x32_bf16(af[mt], bf[jt], acc[mt][jt], 0, 0, 0);
    __syncthreads();
  }
  #pragma unroll
  for (int jt = 0; jt < 4; ++jt) {
    int j = n0 + wc*64 + jt*16 + col;
    if (j >= WCOL) continue;
    float bj = (j < HD) ? b1all[(size_t)l*HD + j] : 0.0f;
    #pragma unroll
    for (int mt = 0; mt < 4; ++mt)
      #pragma unroll
      for (int r = 0; r < 4; ++r) {
        int row = m0 + wr*64 + mt*16 + quad*4 + r;
        short v = (j < HD) ? f2b(ssp_fast(acc[mt][jt][r] + bj)) : (short)0;
        outb[(size_t)row*WCOL + j] = v;
      }
  }
}

// ---------------- tabB: wtab_b[l] = bf16(ttab_all[l]@w2[l] + b2[l]); 128x128 tiles ----------------
__global__ __launch_bounds__(256) void tabB_k(const short* __restrict__ ttab_all,
    const short* __restrict__ nwall, const float* __restrict__ b2all,
    short* __restrict__ wtab_b) {
  const int MT = NKNOT/128;
  int l = blockIdx.x / MT;
  int mb = blockIdx.x - l*MT;
  const short* A  = ttab_all + (size_t)l*NKNOT*WCOL;
  const short* Bw = nwall + (size_t)(18 + l)*WROW*WCOL;   // kind=3 (w2)
  short* P = wtab_b + (size_t)l*NKNOT*HD;
  __shared__ __align__(16) short As[128*40];
  __shared__ __align__(16) short Bs[128*40];
  int tid = threadIdx.x;
  int lane = tid & 63, wv = tid >> 6;
  int wr = wv >> 1, wc = wv & 1;
  int col = lane & 15, quad = lane >> 4;
  int m0 = mb * 128;
  int n0 = blockIdx.y * 128;
  f32x4 acc[4][4] = {};
  for (int k0 = 0; k0 < WCOL; k0 += 32) {
    #pragma unroll
    for (int rep = 0; rep < 2; ++rep) {
      int s = tid + rep*256;
      int row = s >> 2, seg = s & 3;
      *(short8*)&As[row*40 + seg*8] =
          *(const short8*)(A + (size_t)(m0 + row)*WCOL + k0 + seg*8);
      *(short8*)&Bs[row*40 + seg*8] =
          *(const short8*)(Bw + (size_t)(n0 + row)*WCOL + k0 + seg*8);
    }
    __syncthreads();
    short8 af[4], bf[4];
    #pragma unroll
    for (int mt = 0; mt < 4; ++mt)
      af[mt] = *(const short8*)&As[(wr*64 + mt*16 + col)*40 + quad*8];
    #pragma unroll
    for (int jt = 0; jt < 4; ++jt)
      bf[jt] = *(const short8*)&Bs[(wc*64 + jt*16 + col)*40 + quad*8];
    #pragma unroll
    for (int mt = 0; mt < 4; ++mt)
      #pragma unroll
      for (int jt = 0; jt < 4; ++jt)
        acc[mt][jt] = __builtin_amdgcn_mfma_f32_16x16x32_bf16(af[mt], bf[jt], acc[mt][jt], 0, 0, 0);
    __syncthreads();
  }
  #pragma unroll
  for (int jt = 0; jt < 4; ++jt) {
    int j = n0 + wc*64 + jt*16 + col;
    if (j >= HD) continue;
    float bj = b2all[(size_t)l*HD + j];
    #pragma unroll
    for (int mt = 0; mt < 4; ++mt)
      #pragma unroll
      for (int r = 0; r < 4; ++r) {
        int row = m0 + wr*64 + mt*16 + quad*4 + r;
        P[(size_t)row*HD + j] = f2b(acc[mt][jt][r] + bj);
      }
  }
}

// ---------------- shared device bodies (verbatim round-13 arithmetic) ----------------
// gemm tile: 32x64, K=608, single-barrier LDS dbuf
template<int MODE>
__device__ __forceinline__ void gemm_stage(int bx, int by,
    const short* __restrict__ A, const short* __restrict__ Bw,
    const float* __restrict__ bias, short* __restrict__ outb,
    float* __restrict__ hacc, short* AsB, short* BsB) {
  int tid = threadIdx.x;
  int lane = tid & 63, wv = tid >> 6;
  int col = lane & 15, quad = lane >> 4;
  int m0 = bx * 32;
  int n0 = by * 64;
  int ar = tid >> 3, aseg = tid & 7;
  int br = tid >> 2, bseg = tid & 3;
  const short* Aptr = A  + (size_t)(m0 + ar)*WCOL + aseg*4;
  const short* Bptr = Bw + (size_t)(n0 + br)*WCOL + bseg*8;
  f32x4 acc[2] = {};
  {
    short4v a0 = *(const short4v*)Aptr;
    short8  b0 = *(const short8*)Bptr;
    *(short4v*)&AsB[0*32*40 + ar*40 + aseg*4] = a0;
    *(short8*)&BsB[0*64*40 + br*40 + bseg*8] = b0;
  }
  __syncthreads();
  for (int kk = 0; kk < 19; ++kk) {
    int cur = kk & 1, nxt = cur ^ 1;
    short4v a_n; short8 b_n;
    if (kk < 18) {
      a_n = *(const short4v*)(Aptr + (kk + 1)*32);
      b_n = *(const short8*) (Bptr + (kk + 1)*32);
    }
    short8 bf = *(const short8*)&BsB[cur*64*40 + (wv*16 + col)*40 + quad*8];
    #pragma unroll
    for (int mt = 0; mt < 2; ++mt) {
      short8 af = *(const short8*)&AsB[cur*32*40 + (mt*16 + col)*40 + quad*8];
      acc[mt] = __builtin_amdgcn_mfma_f32_16x16x32_bf16(af, bf, acc[mt], 0, 0, 0);
    }
    if (kk < 18) {
      *(short4v*)&AsB[nxt*32*40 + ar*40 + aseg*4] = a_n;
      *(short8*)&BsB[nxt*64*40 + br*40 + bseg*8] = b_n;
    }
    __syncthreads();
  }
  int j = n0 + wv*16 + col;
  if (MODE == 0) {
    if (j < WCOL) {
      #pragma unroll
      for (int mt = 0; mt < 2; ++mt)
        #pragma unroll
        for (int r = 0; r < 4; ++r) {
          int row = m0 + mt*16 + quad*4 + r;
          outb[(size_t)row*WCOL + j] = (j < HD) ? f2b(acc[mt][r]) : (short)0;
        }
    }
  } else if (MODE == 1) {
    if (j < WCOL) {
      float bj = (j < HD) ? bias[j] : 0.0f;
      #pragma unroll
      for (int mt = 0; mt < 2; ++mt)
        #pragma unroll
        for (int r = 0; r < 4; ++r) {
          int row = m0 + mt*16 + quad*4 + r;
          outb[(size_t)row*WCOL + j] = (j < HD) ? f2b(ssp_fast(acc[mt][r] + bj)) : (short)0;
        }
    }
  } else {
    if (j < WCOL) {
      #pragma unroll
      for (int mt = 0; mt < 2; ++mt)
        #pragma unroll
        for (int r = 0; r < 4; ++r) {
          int row = m0 + mt*16 + quad*4 + r;
          if (j < HD) {
            float nv = hacc[(size_t)row*HD + j] + acc[mt][r] + bias[j];
            hacc[(size_t)row*HD + j] = nv;
            outb[(size_t)row*WCOL + j] = f2b(nv);
          } else {
            outb[(size_t)row*WCOL + j] = 0;
          }
        }
    }
  }
}

// gather body for one node (tid*4 column ownership)
__device__ __forceinline__ void gather_body(int node, int tid,
    const short* __restrict__ tabb, const float* __restrict__ cval,
    const int* __restrict__ nbr, const float* __restrict__ dist,
    const short* __restrict__ x1b, short* __restrict__ msgb,
    float* cvs, int* nbs, int* tix, float* tfr) {
  __syncthreads();               // protect LDS reuse across node iterations
  if (tid < 64) {
    int e = node*KNB + tid;
    cvs[tid] = cval[e];
    nbs[tid] = nbr[e];
    float u = dist[e] * ((float)(NKNOT-1)/10.0f);
    int i = (int)u;
    if (i > NKNOT-2) i = NKNOT-2;
    tix[tid] = i;
    tfr[tid] = u - (float)i;
  }
  __syncthreads();
  int j = tid*4;
  if (j >= WCOL) return;
  if (j >= HD) {
    *(uint2*)&msgb[(size_t)node*WCOL + j] = make_uint2(0u, 0u);
    return;
  }
  float s[4] = {0.f, 0.f, 0.f, 0.f};
  #pragma unroll 4
  for (int e = 0; e < KNB; ++e) {
    float Ce = cvs[e];
    if (Ce == 0.0f) continue;
    const short* w0 = tabb + (size_t)tix[e]*HD + j;
    float f = tfr[e];
    uint2 wa = *(const uint2*)w0;
    uint2 wb = *(const uint2*)(w0 + HD);
    uint2 xv = *(const uint2*)(x1b + (size_t)nbs[e]*WCOL + j);
    float a0 = b2f(wa.x & 0xffffu), a1 = b2f(wa.x >> 16);
    float a2 = b2f(wa.y & 0xffffu), a3 = b2f(wa.y >> 16);
    float b0 = b2f(wb.x & 0xffffu), b1 = b2f(wb.x >> 16);
    float b2v = b2f(wb.y & 0xffffu), b3 = b2f(wb.y >> 16);
    float x0 = b2f(xv.x & 0xffffu), x1v = b2f(xv.x >> 16);
    float x2 = b2f(xv.y & 0xffffu), x3 = b2f(xv.y >> 16);
    s[0] += Ce * (a0 + f*(b0 - a0)) * x0;
    s[1] += Ce * (a1 + f*(b1 - a1)) * x1v;
    s[2] += Ce * (a2 + f*(b2v - a2)) * x2;
    s[3] += Ce * (a3 + f*(b3 - a3)) * x3;
  }
  uint2 pack;
  pack.x = (unsigned)(unsigned short)f2b(s[0]) | ((unsigned)(unsigned short)f2b(s[1]) << 16);
  pack.y = (unsigned)(unsigned short)f2b(s[2]) | ((unsigned)(unsigned short)f2b(s[3]) << 16);
  *(uint2*)&msgb[(size_t)node*WCOL + j] = pack;
}

// ---------------- fallback standalone kernels (round-13 dispatch structure) ----------------
template<int MODE>
__global__ __launch_bounds__(256) void gemm_node_k(
    const short* __restrict__ A, const short* __restrict__ Bw,
    const float* __restrict__ bias, short* __restrict__ outb,
    float* __restrict__ hacc) {
  __shared__ __align__(16) short AsB[2*32*40];
  __shared__ __align__(16) short BsB[2*64*40];
  gemm_stage<MODE>(blockIdx.x, blockIdx.y, A, Bw, bias, outb, hacc, AsB, BsB);
}

__global__ __launch_bounds__(192) void gather_k(const short* __restrict__ tabb,
    const float* __restrict__ cval, const int* __restrict__ nbr,
    const float* __restrict__ dist, const short* __restrict__ x1b,
    short* __restrict__ msgb) {
  __shared__ float cvs[64];
  __shared__ int nbs[64];
  __shared__ int tix[64];
  __shared__ float tfr[64];
  gather_body(blockIdx.x, threadIdx.x, tabb, cval, nbr, dist, x1b, msgb,
              cvs, nbs, tix, tfr);
}

__global__ __launch_bounds__(256) void pool_mean_k(const float* __restrict__ h,
                                                   float* __restrict__ pooled) {
  int b = blockIdx.x;
  int c = blockIdx.y*256 + threadIdx.x;
  if (c >= HD) return;
  float s = 0.0f;
  for (int n = 0; n < NPG; ++n) s += h[(size_t)(b*NPG + n)*HD + c];
  pooled[(size_t)b*HD + c] = s * (1.0f/128.0f);
}

__global__ __launch_bounds__(256) void pool_out_k(const float* __restrict__ pooled,
    const float* __restrict__ pw, const float* __restrict__ pb,
    float* __restrict__ out) {
  __shared__ float red[4][64];
  int b = blockIdx.y;
  int tid = threadIdx.x;
  int jl = tid & 63, q = tid >> 6;
  int j = blockIdx.x*64 + jl;
  float s = 0.0f;
  if (j < HD) {
    int c0 = q*150, c1 = c0 + 150;
    for (int c = c0; c < c1; ++c)
      s += pooled[(size_t)b*HD + c] * pw[(size_t)c*HD + j];
  }
  red[q][jl] = s;
  __syncthreads();
  if (q == 0 && j < HD)
    out[(size_t)b*HD + j] = red[0][jl] + red[1][jl] + red[2][jl] + red[3][jl] + pb[j];
}

// ---------------- cooperative mega-kernel: 6 layers + pool, 256 blocks ----------------
__global__ __launch_bounds__(256) void layers_k(
    const short* __restrict__ nwall,
    const float* __restrict__ l2b, const float* __restrict__ ilb,
    const float* __restrict__ cv, const int* __restrict__ nbr,
    const float* __restrict__ dist, const short* __restrict__ wtab_b,
    float* __restrict__ h, short* __restrict__ h_b,
    short* __restrict__ x1_b, short* __restrict__ msg_b,
    short* __restrict__ mtmp_b, float* __restrict__ pooled,
    const float* __restrict__ pw, const float* __restrict__ pb,
    float* __restrict__ out) {
  cg::grid_group grid = cg::this_grid();
  __shared__ __align__(16) short AsB[2*32*40];
  __shared__ __align__(16) short BsB[2*64*40];
  __shared__ float cvs[64];
  __shared__ int nbs[64];
  __shared__ int tix[64];
  __shared__ float tfr[64];
  __shared__ float red[4][64];
  int bid = blockIdx.x;
  int tid = threadIdx.x;
  const size_t WSZ = (size_t)WROW*WCOL;
  for (int l = 0; l < LL; ++l) {
    // A: x1_b = bf16(h @ lin1_w[l])
    for (int t = bid; t < NTILE; t += GRIDB)
      gemm_stage<0>(t & 31, t >> 5, h_b, nwall + (size_t)(0*6 + l)*WSZ,
                    nullptr, x1_b, nullptr, AsB, BsB);
    grid.sync();
    // B: gather
    {
      const short* tabb = wtab_b + (size_t)l*NKNOT*HD;
      for (int node = bid; node < NN; node += GRIDB)
        gather_body(node, tid, tabb, cv, nbr, dist, x1_b, msg_b, cvs, nbs, tix, tfr);
    }
    grid.sync();
    // C: mtmp_b = bf16(ssp(msg @ lin2_w[l] + lin2_b[l]))
    for (int t = bid; t < NTILE; t += GRIDB)
      gemm_stage<1>(t & 31, t >> 5, msg_b, nwall + (size_t)(1*6 + l)*WSZ,
                    l2b + (size_t)l*HD, mtmp_b, nullptr, AsB, BsB);
    grid.sync();
    // D: h += mtmp @ int_lin_w[l] + int_lin_b[l]; h_b = bf16(h)
    for (int t = bid; t < NTILE; t += GRIDB)
      gemm_stage<2>(t & 31, t >> 5, mtmp_b, nwall + (size_t)(2*6 + l)*WSZ,
                    ilb + (size_t)l*HD, h_b, h, AsB, BsB);
    grid.sync();
  }
  // pool mean (blocks 0..23)
  if (bid < 24) {
    int b = bid & 7, cy = bid >> 3;
    int c = cy*256 + tid;
    if (c < HD) {
      float s = 0.0f;
      for (int n = 0; n < NPG; ++n) s += h[(size_t)(b*NPG + n)*HD + c];
      pooled[(size_t)b*HD + c] = s * (1.0f/128.0f);
    }
  }
  grid.sync();
  // pool out (blocks 0..79)
  if (bid < 80) {
    int jx = bid % 10, b = bid / 10;
    int jl = tid & 63, q = tid >> 6;
    int j = jx*64 + jl;
    float s = 0.0f;
    if (j < HD) {
      int c0 = q*150, c1 = c0 + 150;
      for (int c = c0; c < c1; ++c)
        s += pooled[(size_t)b*HD + c] * pw[(size_t)c*HD + j];
    }
    red[q][jl] = s;
    __syncthreads();
    if (q == 0 && j < HD)
      out[(size_t)b*HD + j] = red[0][jl] + red[1][jl] + red[2][jl] + red[3][jl] + pb[j];
  }
}

// ---------------- launch ----------------
extern "C" void kernel_launch(void* const* d_in, const int* in_sizes, int n_in,
                              void* d_out, int out_size, void* d_ws, size_t ws_size,
                              hipStream_t stream) {
  const int*   z    = (const int*)d_in[0];
  const float* pos  = (const float*)d_in[1];
  const float* emb  = (const float*)d_in[2];
  const float* w1   = (const float*)d_in[3];
  const float* b1   = (const float*)d_in[4];
  const float* w2   = (const float*)d_in[5];
  const float* b2   = (const float*)d_in[6];
  const float* l1w  = (const float*)d_in[7];
  const float* l2w  = (const float*)d_in[8];
  const float* l2b  = (const float*)d_in[9];
  const float* ilw  = (const float*)d_in[10];
  const float* ilb  = (const float*)d_in[11];
  const float* pw   = (const float*)d_in[12];
  const float* pb   = (const float*)d_in[13];
  float* ws = (float*)d_ws;
  // workspace layout (float offsets) — total ~10.6M f = 42.4 MB
  int*   nbr   = (int*)ws;                   // 65536
  float* cv    = ws + 65536;                 // 65536
  float* dist  = ws + 131072;                // 65536
  float* pooled= ws + 196608;                // 8192
  float* h     = ws + 204800;                // 614400
  short* h_b   = (short*)(ws + 819200);      // 311296 f
  short* msg_b = (short*)(ws + 1130496);     // 311296 f
  short* mtmp_b= (short*)(ws + 1441792);     // 311296 f
  short* x1_b  = (short*)(ws + 1753088);     // 311296 f
  short* basis = (short*)(ws + 2064384);     // 32768 f
  short* ttab  = (short*)(ws + 2097152);     // 1867776 f
  short* wtab_b= (short*)(ws + 3964928);     // 1843200 f
  short* w1b   = (short*)(ws + 5808128);     // 122880 f
  short* nwall = (short*)(ws + 5931008);     // 4669440 f
  float* out   = (float*)d_out;

  const size_t WSZ = (size_t)WROW*WCOL;

  build_graph_k<<<NN, 128, 0, stream>>>(pos, nbr, dist, cv);
  prep_k<<<(NKNOT*64 + LL*WROW*64 + 255)/256, 256, 0, stream>>>(w1, basis, w1b);
  conv_all_k<<<dim3(24, 10, 10), 256, 0, stream>>>(l1w, l2w, ilw, w2, nwall);
  embed_k<<<NN, 256, 0, stream>>>(z, emb, h, h_b);

  // batched W(d) tables for all layers
  tabA_k<<<dim3(LL*(NKNOT/128), 5), 256, 0, stream>>>(basis, w1b, b1, ttab);
  tabB_k<<<dim3(LL*(NKNOT/128), 5), 256, 0, stream>>>(ttab, nwall, b2, wtab_b);

  // cooperative mega-kernel (bitwise-identical to fallback); fallback if rejected
  void* args[] = {
    (void*)&nwall, (void*)&l2b, (void*)&ilb, (void*)&cv, (void*)&nbr,
    (void*)&dist, (void*)&wtab_b, (void*)&h, (void*)&h_b, (void*)&x1_b,
    (void*)&msg_b, (void*)&mtmp_b, (void*)&pooled, (void*)&pw, (void*)&pb,
    (void*)&out
  };
  hipError_t ce = hipLaunchCooperativeKernel((const void*)layers_k, dim3(GRIDB),
                                             dim3(256), args, 0, stream);
  if (ce != hipSuccess) {
    dim3 gn(32, 10);
    for (int l = 0; l < LL; ++l) {
      gemm_node_k<0><<<gn, 256, 0, stream>>>(h_b, nwall + (size_t)(0*6 + l)*WSZ,
          nullptr, x1_b, nullptr);
      gather_k<<<NN, 192, 0, stream>>>(wtab_b + (size_t)l*NKNOT*HD, cv, nbr, dist,
          x1_b, msg_b);
      gemm_node_k<1><<<gn, 256, 0, stream>>>(msg_b, nwall + (size_t)(1*6 + l)*WSZ,
          l2b + (size_t)l*HD, mtmp_b, nullptr);
      gemm_node_k<2><<<gn, 256, 0, stream>>>(mtmp_b, nwall + (size_t)(2*6 + l)*WSZ,
          ilb + (size_t)l*HD, h_b, h);
    }
    pool_mean_k<<<dim3(NB, 3), 256, 0, stream>>>(h, pooled);
    pool_out_k<<<dim3(10, NB), 256, 0, stream>>>(pooled, pw, pb, out);
  }
}

// Round 16
// 538.913 us; speedup vs baseline: 2.8719x; 2.8719x over previous
//
#include <hip/hip_runtime.h>
#include <cmath>

#define NB   8
#define NPG  128
#define NN   1024
#define KNB  64
#define HD   600
#define GG   50
#define LL   6
#define EE   (NN*KNB)     // 65536 edges
#define WROW 640          // padded weight rows (n)
#define WCOL 608          // padded weight cols (k)
#define NKNOT 1024        // W(d) table knots over [0,10]

typedef __attribute__((ext_vector_type(8))) short short8;
typedef __attribute__((ext_vector_type(4))) short short4v;
typedef __attribute__((ext_vector_type(4))) float f32x4;

__device__ __forceinline__ short f2b(float f) {
  union { float f; unsigned u; } v; v.f = f;
  unsigned u = v.u;
  u += 0x7fffu + ((u >> 16) & 1u);
  return (short)(u >> 16);
}

__device__ __forceinline__ float b2f(unsigned us) {
  union { unsigned u; float f; } v; v.u = us << 16; return v.f;
}

// fast shifted softplus: max(x,0)+log(1+e^-|x|)-ln2
__device__ __forceinline__ float ssp_fast(float x) {
  return fmaxf(x, 0.0f) + __logf(1.0f + __expf(-fabsf(x))) - 0.69314718055994531f;
}

// ---------------- graph build: one block per node ----------------
__global__ __launch_bounds__(128) void build_graph_k(const float* __restrict__ pos,
        int* __restrict__ nbr, float* __restrict__ dist, float* __restrict__ cval) {
#pragma clang fp contract(off)
  __shared__ float d2s[128];
  __shared__ int scnt;
  int i = blockIdx.x;
  int li = i & 127;
  int base = i - li;
  int j = threadIdx.x;
  if (j == 0) scnt = 0;
  float px = pos[3*i], py = pos[3*i+1], pz = pos[3*i+2];
  int gj = base + j;
  float dx = px - pos[3*gj], dy = py - pos[3*gj+1], dz = pz - pos[3*gj+2];
  float d2 = dx*dx + dy*dy + dz*dz;
  bool valid = (j != li) && (d2 <= 100.0f);
  d2s[j] = valid ? d2 : 3.0e38f;
  __syncthreads();
  if (valid) {
    atomicAdd(&scnt, 1);
    int rank = 0;
    for (int j2 = 0; j2 < 128; ++j2) {
      float o = d2s[j2];
      rank += (o < d2 || (o == d2 && j2 < j)) ? 1 : 0;
    }
    if (rank < KNB) {
      int e = i*KNB + rank;
      nbr[e] = gj;
      float d = sqrtf(d2);
      dist[e] = d;
      cval[e] = 0.5f * (cosf(d * 0.31415926535897931f) + 1.0f);
    }
  }
  __syncthreads();
  int cnt = scnt; if (cnt > KNB) cnt = KNB;
  if (j < KNB && j >= cnt) {
    int e = i*KNB + j;
    nbr[e] = i; dist[e] = 0.0f; cval[e] = 0.0f;
  }
}

// ---------------- prep: gaussian basis [NKNOT][64] + w1 conv [6][640][64] ----------------
__global__ __launch_bounds__(256) void prep_k(const float* __restrict__ w1,
    short* __restrict__ basis, short* __restrict__ w1b) {
  int idx = blockIdx.x*256 + threadIdx.x;
  if (idx < NKNOT*64) {
    int i = idx >> 6, g = idx & 63;
    float v = 0.0f;
    if (g < GG) {
      const float step = 10.0f/49.0f;
      const float coeff = -0.5f/(step*step);
      float d = (float)i * (10.0f/(float)(NKNOT-1));
      float dd = d - step*(float)g;
      v = __expf(coeff*dd*dd);
    }
    basis[idx] = f2b(v);
  } else {
    int r = idx - NKNOT*64;
    if (r >= LL*WROW*64) return;
    int l = r / (WROW*64); int rem = r - l*WROW*64;
    int n = rem >> 6, k = rem & 63;
    float v = (n < HD && k < GG) ? w1[(size_t)l*GG*HD + (size_t)k*HD + n] : 0.0f;
    w1b[r] = f2b(v);
  }
}

// ---------------- all node/w2 weights: LDS-tiled transpose ----------------
__global__ __launch_bounds__(256) void conv_all_k(const float* __restrict__ l1w,
    const float* __restrict__ l2w, const float* __restrict__ ilw,
    const float* __restrict__ w2, short* __restrict__ dst) {
  __shared__ float T[64][65];
  int w = blockIdx.x;
  int kind = w / 6, l = w - kind*6;
  const float* s = (kind == 0) ? l1w : (kind == 1) ? l2w : (kind == 2) ? ilw : w2;
  s += (size_t)l*360000;
  int n0 = blockIdx.y*64, k0 = blockIdx.z*64;
  int tid = threadIdx.x;
  int ta = tid & 63, tb = tid >> 6;
  #pragma unroll
  for (int p = 0; p < 16; ++p) {
    int k = k0 + p*4 + tb;
    int n = n0 + ta;
    T[p*4 + tb][ta] = (k < HD && n < HD) ? s[(size_t)k*HD + n] : 0.0f;
  }
  __syncthreads();
  #pragma unroll
  for (int p = 0; p < 16; ++p) {
    int n = n0 + p*4 + tb;
    int k = k0 + ta;
    if (k < WCOL)
      dst[(size_t)w*WROW*WCOL + (size_t)n*WCOL + k] = f2b(T[ta][p*4 + tb]);
  }
}

// ---------------- embedding: h fp32 + h_b bf16 ----------------
__global__ __launch_bounds__(256) void embed_k(const int* __restrict__ z,
        const float* __restrict__ emb, float* __restrict__ h, short* __restrict__ hb) {
  int i = blockIdx.x;
  int zi = z[i];
  for (int j = threadIdx.x; j < WCOL; j += 256) {
    float v = (j < HD) ? emb[(size_t)zi*HD + j] : 0.0f;
    if (j < HD) h[(size_t)i*HD + j] = v;
    hb[(size_t)i*WCOL + j] = f2b(v);
  }
}

// ---------------- tab_fused: per 64-row block, ttab rows in LDS, then wtab ----------------
// grid: 6 layers x 16 row-blocks. Phase1 = tabA arithmetic (K=64, MFMA 16x16x32,
// k ascending); phase2 = tabB arithmetic (K=608, k ascending). Bitwise-identical
// per output element to the round-13 tabA/tabB pair.
__global__ __launch_bounds__(256) void tab_fused_k(const short* __restrict__ basis,
    const short* __restrict__ w1b, const float* __restrict__ b1all,
    const short* __restrict__ nwall, const float* __restrict__ b2all,
    short* __restrict__ wtab_b) {
  __shared__ __align__(16) short T[64*616];   // 78.8 KB: 64 ttab rows, pads zeroed
  int blk = blockIdx.x;
  int l = blk >> 4, rb = blk & 15;
  int m0 = rb * 64;
  const short* w1l = w1b + (size_t)l*WROW*64;
  const short* w2l = nwall + (size_t)(18 + l)*WROW*WCOL;   // kind=3 (w2)
  short* P = wtab_b + (size_t)l*NKNOT*HD;
  int tid = threadIdx.x;
  int lane = tid & 63, wv = tid >> 6;
  int wr = wv >> 1, wc = wv & 1;
  int col = lane & 15, quad = lane >> 4;
  // phase 1: T[row][j] = bf16(ssp(basis@w1 + b1)), 64x64 tiles over 10 col-tiles
  for (int ct = 0; ct < 10; ++ct) {
    int n0 = ct*64;
    f32x4 acc[2][2] = {};
    #pragma unroll
    for (int k0 = 0; k0 < 64; k0 += 32) {
      short8 af[2], bf[2];
      #pragma unroll
      for (int mt = 0; mt < 2; ++mt)
        af[mt] = *(const short8*)(basis + (size_t)(m0 + wr*32 + mt*16 + col)*64 + k0 + quad*8);
      #pragma unroll
      for (int jt = 0; jt < 2; ++jt)
        bf[jt] = *(const short8*)(w1l + (size_t)(n0 + wc*32 + jt*16 + col)*64 + k0 + quad*8);
      #pragma unroll
      for (int mt = 0; mt < 2; ++mt)
        #pragma unroll
        for (int jt = 0; jt < 2; ++jt)
          acc[mt][jt] = __builtin_amdgcn_mfma_f32_16x16x32_bf16(af[mt], bf[jt], acc[mt][jt], 0, 0, 0);
    }
    #pragma unroll
    for (int jt = 0; jt < 2; ++jt) {
      int j = n0 + wc*32 + jt*16 + col;
      if (j >= WCOL) continue;
      float bj = (j < HD) ? b1all[(size_t)l*HD + j] : 0.0f;
      #pragma unroll
      for (int mt = 0; mt < 2; ++mt)
        #pragma unroll
        for (int r = 0; r < 4; ++r) {
          int row = wr*32 + mt*16 + quad*4 + r;
          short v = (j < HD) ? f2b(ssp_fast(acc[mt][jt][r] + bj)) : (short)0;
          T[row*616 + j] = v;
        }
    }
  }
  __syncthreads();
  // phase 2: wtab rows = T @ w2 + b2
  for (int ct = 0; ct < 10; ++ct) {
    int n0 = ct*64;
    f32x4 acc[2][2] = {};
    for (int k0 = 0; k0 < WCOL; k0 += 32) {
      short8 af[2], bf[2];
      #pragma unroll
      for (int mt = 0; mt < 2; ++mt)
        af[mt] = *(const short8*)&T[(wr*32 + mt*16 + col)*616 + k0 + quad*8];
      #pragma unroll
      for (int jt = 0; jt < 2; ++jt)
        bf[jt] = *(const short8*)(w2l + (size_t)(n0 + wc*32 + jt*16 + col)*WCOL + k0 + quad*8);
      #pragma unroll
      for (int mt = 0; mt < 2; ++mt)
        #pragma unroll
        for (int jt = 0; jt < 2; ++jt)
          acc[mt][jt] = __builtin_amdgcn_mfma_f32_16x16x32_bf16(af[mt], bf[jt], acc[mt][jt], 0, 0, 0);
    }
    #pragma unroll
    for (int jt = 0; jt < 2; ++jt) {
      int j = n0 + wc*32 + jt*16 + col;
      if (j >= HD) continue;
      float bj = b2all[(size_t)l*HD + j];
      #pragma unroll
      for (int mt = 0; mt < 2; ++mt)
        #pragma unroll
        for (int r = 0; r < 4; ++r) {
          int row = m0 + wr*32 + mt*16 + quad*4 + r;
          P[(size_t)row*HD + j] = f2b(acc[mt][jt][r] + bj);
        }
    }
  }
}

// ---------------- gather: msg_b[node] = bf16(sum_e C_e * Wtab(d_e) (.) x1[nbr_e]) ----------------
__global__ __launch_bounds__(192) void gather_k(const short* __restrict__ tabb,
    const float* __restrict__ cval, const int* __restrict__ nbr,
    const float* __restrict__ dist, const short* __restrict__ x1b,
    short* __restrict__ msgb) {
  __shared__ float cvs[64];
  __shared__ int nbs[64];
  __shared__ int tix[64];
  __shared__ float tfr[64];
  int node = blockIdx.x, tid = threadIdx.x;
  if (tid < 64) {
    int e = node*KNB + tid;
    cvs[tid] = cval[e];
    nbs[tid] = nbr[e];
    float u = dist[e] * ((float)(NKNOT-1)/10.0f);
    int i = (int)u;
    if (i > NKNOT-2) i = NKNOT-2;
    tix[tid] = i;
    tfr[tid] = u - (float)i;
  }
  __syncthreads();
  int j = tid*4;
  if (j >= WCOL) return;
  if (j >= HD) {
    *(uint2*)&msgb[(size_t)node*WCOL + j] = make_uint2(0u, 0u);
    return;
  }
  float s[4] = {0.f, 0.f, 0.f, 0.f};
  #pragma unroll 4
  for (int e = 0; e < KNB; ++e) {
    float Ce = cvs[e];
    if (Ce == 0.0f) continue;
    const short* w0 = tabb + (size_t)tix[e]*HD + j;
    float f = tfr[e];
    uint2 wa = *(const uint2*)w0;
    uint2 wb = *(const uint2*)(w0 + HD);
    uint2 xv = *(const uint2*)(x1b + (size_t)nbs[e]*WCOL + j);
    float a0 = b2f(wa.x & 0xffffu), a1 = b2f(wa.x >> 16);
    float a2 = b2f(wa.y & 0xffffu), a3 = b2f(wa.y >> 16);
    float b0 = b2f(wb.x & 0xffffu), b1 = b2f(wb.x >> 16);
    float b2v = b2f(wb.y & 0xffffu), b3 = b2f(wb.y >> 16);
    float x0 = b2f(xv.x & 0xffffu), x1v = b2f(xv.x >> 16);
    float x2 = b2f(xv.y & 0xffffu), x3 = b2f(xv.y >> 16);
    s[0] += Ce * (a0 + f*(b0 - a0)) * x0;
    s[1] += Ce * (a1 + f*(b1 - a1)) * x1v;
    s[2] += Ce * (a2 + f*(b2v - a2)) * x2;
    s[3] += Ce * (a3 + f*(b3 - a3)) * x3;
  }
  uint2 pack;
  pack.x = (unsigned)(unsigned short)f2b(s[0]) | ((unsigned)(unsigned short)f2b(s[1]) << 16);
  pack.y = (unsigned)(unsigned short)f2b(s[2]) | ((unsigned)(unsigned short)f2b(s[3]) << 16);
  *(uint2*)&msgb[(size_t)node*WCOL + j] = pack;
}

// ---------------- fused node GEMM: 32x64 tile, single-barrier LDS double-buffer ----------------
// grid (32, 10). MODE 0: x1_b; MODE 1: ssp->mtmp_b; MODE 2: residual -> h, h_b
template<int MODE>
__global__ __launch_bounds__(256) void gemm_node_k(
    const short* __restrict__ A, const short* __restrict__ Bw,
    const float* __restrict__ bias, short* __restrict__ outb,
    float* __restrict__ hacc) {
  __shared__ __align__(16) short As[2][32*40];
  __shared__ __align__(16) short Bs[2][64*40];
  int tid = threadIdx.x;
  int lane = tid & 63, wv = tid >> 6;
  int col = lane & 15, quad = lane >> 4;
  int m0 = blockIdx.x * 32;
  int n0 = blockIdx.y * 64;
  int ar = tid >> 3, aseg = tid & 7;
  int br = tid >> 2, bseg = tid & 3;
  const short* Aptr = A  + (size_t)(m0 + ar)*WCOL + aseg*4;
  const short* Bptr = Bw + (size_t)(n0 + br)*WCOL + bseg*8;
  f32x4 acc[2] = {};
  {
    short4v a0 = *(const short4v*)Aptr;
    short8  b0 = *(const short8*)Bptr;
    *(short4v*)&As[0][ar*40 + aseg*4] = a0;
    *(short8*)&Bs[0][br*40 + bseg*8] = b0;
  }
  __syncthreads();
  for (int kk = 0; kk < 19; ++kk) {
    int cur = kk & 1, nxt = cur ^ 1;
    short4v a_n; short8 b_n;
    if (kk < 18) {
      a_n = *(const short4v*)(Aptr + (kk + 1)*32);
      b_n = *(const short8*) (Bptr + (kk + 1)*32);
    }
    short8 bf = *(const short8*)&Bs[cur][(wv*16 + col)*40 + quad*8];
    #pragma unroll
    for (int mt = 0; mt < 2; ++mt) {
      short8 af = *(const short8*)&As[cur][(mt*16 + col)*40 + quad*8];
      acc[mt] = __builtin_amdgcn_mfma_f32_16x16x32_bf16(af, bf, acc[mt], 0, 0, 0);
    }
    if (kk < 18) {
      *(short4v*)&As[nxt][ar*40 + aseg*4] = a_n;
      *(short8*)&Bs[nxt][br*40 + bseg*8] = b_n;
    }
    __syncthreads();
  }
  int j = n0 + wv*16 + col;
  if (MODE == 0) {
    if (j < WCOL) {
      #pragma unroll
      for (int mt = 0; mt < 2; ++mt)
        #pragma unroll
        for (int r = 0; r < 4; ++r) {
          int row = m0 + mt*16 + quad*4 + r;
          outb[(size_t)row*WCOL + j] = (j < HD) ? f2b(acc[mt][r]) : (short)0;
        }
    }
  } else if (MODE == 1) {
    if (j < WCOL) {
      float bj = (j < HD) ? bias[j] : 0.0f;
      #pragma unroll
      for (int mt = 0; mt < 2; ++mt)
        #pragma unroll
        for (int r = 0; r < 4; ++r) {
          int row = m0 + mt*16 + quad*4 + r;
          outb[(size_t)row*WCOL + j] = (j < HD) ? f2b(ssp_fast(acc[mt][r] + bj)) : (short)0;
        }
    }
  } else {
    if (j < WCOL) {
      #pragma unroll
      for (int mt = 0; mt < 2; ++mt)
        #pragma unroll
        for (int r = 0; r < 4; ++r) {
          int row = m0 + mt*16 + quad*4 + r;
          if (j < HD) {
            float nv = hacc[(size_t)row*HD + j] + acc[mt][r] + bias[j];
            hacc[(size_t)row*HD + j] = nv;
            outb[(size_t)row*WCOL + j] = f2b(nv);
          } else {
            outb[(size_t)row*WCOL + j] = 0;
          }
        }
    }
  }
}

// ---------------- fused pool: out[b] = mean_n(h[b]) @ pw + pb ----------------
// grid (10, 8); ps[c] computed per block with pool_mean's exact summation order.
__global__ __launch_bounds__(256) void pool_k(const float* __restrict__ h,
    const float* __restrict__ pw, const float* __restrict__ pb,
    float* __restrict__ out) {
  __shared__ float ps[HD];
  __shared__ float red[4][64];
  int b = blockIdx.y;
  int tid = threadIdx.x;
  for (int c = tid; c < HD; c += 256) {
    float s = 0.0f;
    for (int n = 0; n < NPG; ++n) s += h[(size_t)(b*NPG + n)*HD + c];
    ps[c] = s * (1.0f/128.0f);
  }
  __syncthreads();
  int jl = tid & 63, q = tid >> 6;
  int j = blockIdx.x*64 + jl;
  float s = 0.0f;
  if (j < HD) {
    int c0 = q*150, c1 = c0 + 150;
    for (int c = c0; c < c1; ++c)
      s += ps[c] * pw[(size_t)c*HD + j];
  }
  red[q][jl] = s;
  __syncthreads();
  if (q == 0 && j < HD)
    out[(size_t)b*HD + j] = red[0][jl] + red[1][jl] + red[2][jl] + red[3][jl] + pb[j];
}

// ---------------- launch ----------------
extern "C" void kernel_launch(void* const* d_in, const int* in_sizes, int n_in,
                              void* d_out, int out_size, void* d_ws, size_t ws_size,
                              hipStream_t stream) {
  const int*   z    = (const int*)d_in[0];
  const float* pos  = (const float*)d_in[1];
  const float* emb  = (const float*)d_in[2];
  const float* w1   = (const float*)d_in[3];
  const float* b1   = (const float*)d_in[4];
  const float* w2   = (const float*)d_in[5];
  const float* b2   = (const float*)d_in[6];
  const float* l1w  = (const float*)d_in[7];
  const float* l2w  = (const float*)d_in[8];
  const float* l2b  = (const float*)d_in[9];
  const float* ilw  = (const float*)d_in[10];
  const float* ilb  = (const float*)d_in[11];
  const float* pw   = (const float*)d_in[12];
  const float* pb   = (const float*)d_in[13];
  float* ws = (float*)d_ws;
  // workspace layout (float offsets)
  int*   nbr   = (int*)ws;                   // 65536
  float* cv    = ws + 65536;                 // 65536
  float* dist  = ws + 131072;                // 65536
  float* h     = ws + 204800;                // 614400
  short* h_b   = (short*)(ws + 819200);      // 311296 f
  short* msg_b = (short*)(ws + 1130496);     // 311296 f
  short* mtmp_b= (short*)(ws + 1441792);     // 311296 f
  short* x1_b  = (short*)(ws + 1753088);     // 311296 f
  short* basis = (short*)(ws + 2064384);     // 32768 f
  short* wtab_b= (short*)(ws + 3964928);     // 1843200 f
  short* w1b   = (short*)(ws + 5808128);     // 122880 f
  short* nwall = (short*)(ws + 5931008);     // 4669440 f
  float* out   = (float*)d_out;

  const size_t WSZ = (size_t)WROW*WCOL;

  build_graph_k<<<NN, 128, 0, stream>>>(pos, nbr, dist, cv);
  prep_k<<<(NKNOT*64 + LL*WROW*64 + 255)/256, 256, 0, stream>>>(w1, basis, w1b);
  conv_all_k<<<dim3(24, 10, 10), 256, 0, stream>>>(l1w, l2w, ilw, w2, nwall);
  embed_k<<<NN, 256, 0, stream>>>(z, emb, h, h_b);

  // fused W(d) tables for all layers (tabA+tabB, ttab stays in LDS)
  tab_fused_k<<<LL*16, 256, 0, stream>>>(basis, w1b, b1, nwall, b2, wtab_b);

  dim3 gn(32, 10);
  for (int l = 0; l < LL; ++l) {
    // x1_b = bf16(h @ lin1_w[l])
    gemm_node_k<0><<<gn, 256, 0, stream>>>(h_b, nwall + (size_t)(0*6 + l)*WSZ,
        nullptr, x1_b, nullptr);
    // msg_b[node] = bf16(sum_e C_e * Wtab(d_e) (.) x1[nbr_e])
    gather_k<<<NN, 192, 0, stream>>>(wtab_b + (size_t)l*NKNOT*HD, cv, nbr, dist, x1_b, msg_b);
    // mtmp_b = bf16(ssp(msg @ lin2_w[l] + lin2_b[l]))
    gemm_node_k<1><<<gn, 256, 0, stream>>>(msg_b, nwall + (size_t)(1*6 + l)*WSZ,
        l2b + (size_t)l*HD, mtmp_b, nullptr);
    // h += mtmp @ int_lin_w[l] + int_lin_b[l]; h_b = bf16(h)
    gemm_node_k<2><<<gn, 256, 0, stream>>>(mtmp_b, nwall + (size_t)(2*6 + l)*WSZ,
        ilb + (size_t)l*HD, h_b, h);
  }
  pool_k<<<dim3(10, NB), 256, 0, stream>>>(h, pw, pb, out);
}